// Round 3
// 1159.315 us; speedup vs baseline: 1.0904x; 1.0904x over previous
//
#include <hip/hip_runtime.h>
#include <stdint.h>

typedef __attribute__((ext_vector_type(8))) short short8;
typedef __attribute__((ext_vector_type(4))) float f32x4;

#define LDST 72       // LDS row stride in bf16 elems (64 + 8 pad; 144B keeps 16B align)
#define SCAN_TILE 4096

__device__ __forceinline__ float bf2f(unsigned short u) {
  union { unsigned int i; float f; } v;
  v.i = ((unsigned int)u) << 16;
  return v.f;
}
__device__ __forceinline__ unsigned short f2bf(float f) {
  union { float f; unsigned int i; } v;
  v.f = f;
  unsigned int u = v.i;
  return (unsigned short)((u + 0x7FFFu + ((u >> 16) & 1u)) >> 16);
}
__device__ __forceinline__ unsigned int pack2(float a, float b) {
  return (unsigned int)f2bf(a) | ((unsigned int)f2bf(b) << 16);
}
__device__ __forceinline__ void add2(float& a, float& b, unsigned int v) {
  a += bf2f((unsigned short)(v & 0xffff));
  b += bf2f((unsigned short)(v >> 16));
}

// ---------------------------------------------------------------------------
// All six weight transposes (fp32 -> bf16, [K,N] -> [N,K-concat]) in one launch.
// ---------------------------------------------------------------------------
__global__ __launch_bounds__(256) void build_wt_all(
    const float* __restrict__ Wl1ui, const float* __restrict__ Wr1ui,
    const float* __restrict__ Wl1iu, const float* __restrict__ Wr1iu,
    const float* __restrict__ Wl2ui, const float* __restrict__ Wr2ui,
    const float* __restrict__ Wl2iu, const float* __restrict__ Wr2iu,
    unsigned short* __restrict__ WT1ui, unsigned short* __restrict__ WT1iu,
    unsigned short* __restrict__ WT2lui, unsigned short* __restrict__ WT2rui,
    unsigned short* __restrict__ WT2liu, unsigned short* __restrict__ WT2riu)
{
  int idx = blockIdx.x * 256 + threadIdx.x;
  const float *W1, *W2 = nullptr;
  unsigned short* WT;
  int K1, N, rel;
  if (idx < 65536)       { W1 = Wl1ui; W2 = Wr1ui; WT = WT1ui;  K1 = 128; N = 256; rel = idx; }
  else if (idx < 131072) { W1 = Wl1iu; W2 = Wr1iu; WT = WT1iu;  K1 = 128; N = 256; rel = idx - 65536; }
  else if (idx < 163840) { W1 = Wl2ui;             WT = WT2lui; K1 = 256; N = 128; rel = idx - 131072; }
  else if (idx < 196608) { W1 = Wr2ui;             WT = WT2rui; K1 = 256; N = 128; rel = idx - 163840; }
  else if (idx < 229376) { W1 = Wl2iu;             WT = WT2liu; K1 = 256; N = 128; rel = idx - 196608; }
  else                   { W1 = Wr2iu;             WT = WT2riu; K1 = 256; N = 128; rel = idx - 229376; }
  int n = rel >> 8;
  int k = rel & 255;
  float v = (k < K1) ? W1[(size_t)k * N + n] : W2[(size_t)(k - K1) * N + n];
  WT[rel] = f2bf(v);
}

// ---------------------------------------------------------------------------
// CSR build over COMBINED node space (items [0,NI), users [NI,NI+NU)).
// ---------------------------------------------------------------------------
__global__ __launch_bounds__(256) void hist(
    const int* __restrict__ esrc, const int* __restrict__ edst,
    int* __restrict__ cntAll, int NI, int E)
{
  int e = blockIdx.x * 256 + threadIdx.x;
  if (e >= E) return;
  atomicAdd(&cntAll[edst[e]], 1);
  atomicAdd(&cntAll[NI + esrc[e]], 1);
}

__global__ __launch_bounds__(256) void scan_p1(
    const int* __restrict__ cnt, int* __restrict__ tileSums, int NA)
{
  __shared__ int red[256];
  int b = blockIdx.x, t = threadIdx.x;
  int base = b * SCAN_TILE;
  int s = 0;
  for (int i = t; i < SCAN_TILE; i += 256) {
    int g = base + i;
    if (g < NA) s += cnt[g];
  }
  red[t] = s;
  __syncthreads();
  for (int d = 128; d > 0; d >>= 1) {
    if (t < d) red[t] += red[t + d];
    __syncthreads();
  }
  if (t == 0) tileSums[b] = red[0];
}

__global__ __launch_bounds__(256) void scan_p2(
    int* __restrict__ tileSums, int nTiles, int* __restrict__ offEnd)
{
  __shared__ int buf[256];
  int t = threadIdx.x;
  int v = (t < nTiles) ? tileSums[t] : 0;
  buf[t] = v;
  __syncthreads();
  for (int d = 1; d < 256; d <<= 1) {
    int x = (t >= d) ? buf[t - d] : 0;
    __syncthreads();
    buf[t] += x;
    __syncthreads();
  }
  if (t < nTiles) tileSums[t] = buf[t] - v;   // exclusive
  if (t == nTiles - 1) *offEnd = buf[t];      // grand total -> offAll[NA]
}

__global__ __launch_bounds__(256) void scan_p3(
    const int* __restrict__ cnt, const int* __restrict__ tileSums,
    int* __restrict__ off, int NA)
{
  __shared__ int red[256];
  int b = blockIdx.x, t = threadIdx.x;
  int base = b * SCAN_TILE + t * 16;
  int loc[16];
  int s = 0;
#pragma unroll
  for (int i = 0; i < 16; ++i) {
    int g = base + i;
    loc[i] = (g < NA) ? cnt[g] : 0;
    s += loc[i];
  }
  red[t] = s;
  __syncthreads();
  for (int d = 1; d < 256; d <<= 1) {
    int x = (t >= d) ? red[t - d] : 0;
    __syncthreads();
    red[t] += x;
    __syncthreads();
  }
  int run = tileSums[b] + red[t] - s;  // exclusive base for this thread
#pragma unroll
  for (int i = 0; i < 16; ++i) {
    int g = base + i;
    if (g < NA) off[g] = run;
    run += loc[i];
  }
}

__global__ __launch_bounds__(256) void fill_idx(
    const int* __restrict__ esrc, const int* __restrict__ edst,
    const int* __restrict__ offAll, int* __restrict__ curAll,
    int* __restrict__ idxAll, int NI, int E)
{
  int e = blockIdx.x * 256 + threadIdx.x;
  if (e >= E) return;
  int s = esrc[e], d = edst[e];
  int pI = offAll[d] + atomicAdd(&curAll[d], 1);
  idxAll[pI] = s;                     // item d aggregates user rows
  int pU = offAll[NI + s] + atomicAdd(&curAll[NI + s], 1);
  idxAll[pU] = d;                     // user s aggregates item rows
}

// ---------------------------------------------------------------------------
// Layer-1 aggregation, both node types in one launch. One wave per node.
// MLP-optimized: two 32-lane halves each read a FULL 512B row via float4;
// halves take alternate neighbors; inner loop 2x-unrolled -> up to 4 rows
// in flight per wave (vs 1 before). Halves combined with one shfl_xor(32).
// Emits Acat[n] = [mean_neighbors | x_self] bf16 ([*,256]).
// ---------------------------------------------------------------------------
__global__ __launch_bounds__(256) void build_acat(
    const float* __restrict__ xu, const float* __restrict__ xi,
    const int* __restrict__ idxAll, const int* __restrict__ offAll,
    unsigned int* __restrict__ AcatI, unsigned int* __restrict__ AcatU,
    int NI, int NA)
{
  int w = (blockIdx.x * 256 + threadIdx.x) >> 6;
  if (w >= NA) return;
  int l = threadIdx.x & 63;
  int h = l >> 5;                          // half id (0/1)
  int lh = l & 31;                         // lane within half
  bool isItem = (w < NI);
  const float* xo = isItem ? xu : xi;      // neighbor features
  const float* xs = isItem ? xi : xu;      // self features
  unsigned int* Acat = isItem ? AcatI : AcatU;
  int n = isItem ? w : (w - NI);
  int s = offAll[w], e = offAll[w + 1];

  // hoist self-feature load (upper half only) so it overlaps the gather loop
  f32x4 xv = (f32x4){0.f, 0.f, 0.f, 0.f};
  if (h) xv = *(const f32x4*)(xs + (size_t)n * 128 + lh * 4);

  f32x4 acc = (f32x4){0.f, 0.f, 0.f, 0.f};
  int j = s + h;                           // this half's neighbor stream (stride 2)
  for (; j + 2 < e; j += 4) {              // 2 rows per half in flight
    int g0 = idxAll[j];
    int g1 = idxAll[j + 2];
    f32x4 v0 = *(const f32x4*)(xo + (size_t)g0 * 128 + lh * 4);
    f32x4 v1 = *(const f32x4*)(xo + (size_t)g1 * 128 + lh * 4);
    acc += v0 + v1;
  }
  if (j < e) {
    int g = idxAll[j];
    acc += *(const f32x4*)(xo + (size_t)g * 128 + lh * 4);
  }

  // combine halves: every lane ends with full sum of its 4 elements
#pragma unroll
  for (int c = 0; c < 4; ++c)
    acc[c] += __shfl_xor(acc[c], 32, 64);

  float inv = 1.0f / (float)max(e - s, 1);
  if (h == 0) {                            // lower half writes mean (256B)
    uint2 o;
    o.x = pack2(acc[0] * inv, acc[1] * inv);
    o.y = pack2(acc[2] * inv, acc[3] * inv);
    *(uint2*)(Acat + (size_t)n * 128 + lh * 2) = o;
  } else {                                 // upper half writes self (256B)
    uint2 o;
    o.x = pack2(xv[0], xv[1]);
    o.y = pack2(xv[2], xv[3]);
    *(uint2*)(Acat + (size_t)n * 128 + 64 + lh * 2) = o;
  }
}

// ---------------------------------------------------------------------------
// Layer-2 aggregation, both node types in one launch. One wave per node.
// MLP-optimized: four 16-lane quarters each read a FULL 256B bf16 row via
// uint4; quarters take every 4th neighbor; 2x-unrolled -> up to 8 rows in
// flight. Cross-quarter reduce via shfl_xor(16)+shfl_xor(32).
// m2[n] = mean of projected neighbor rows (bf16 in, bf16 out).
// ---------------------------------------------------------------------------
__global__ __launch_bounds__(256) void seg_mean(
    const unsigned int* __restrict__ pU, const unsigned int* __restrict__ pI,
    const int* __restrict__ idxAll, const int* __restrict__ offAll,
    unsigned int* __restrict__ m2I, unsigned int* __restrict__ m2U,
    int NI, int NA)
{
  int w = (blockIdx.x * 256 + threadIdx.x) >> 6;
  if (w >= NA) return;
  int l = threadIdx.x & 63;
  int q = l >> 4;                          // quarter id (0..3)
  int lq = l & 15;                         // lane within quarter
  bool isItem = (w < NI);
  const unsigned int* p = isItem ? pU : pI;
  unsigned int* m2 = isItem ? m2I : m2U;
  int n = isItem ? w : (w - NI);
  int s = offAll[w], e = offAll[w + 1];

  float a0 = 0.f, a1 = 0.f, a2 = 0.f, a3 = 0.f,
        a4 = 0.f, a5 = 0.f, a6 = 0.f, a7 = 0.f;

  int j = s + q;                           // this quarter's stream (stride 4)
  for (; j + 4 < e; j += 8) {              // 2 rows per quarter in flight
    int g0 = idxAll[j];
    int g1 = idxAll[j + 4];
    uint4 v0 = *(const uint4*)(p + (size_t)g0 * 64 + lq * 4);
    uint4 v1 = *(const uint4*)(p + (size_t)g1 * 64 + lq * 4);
    add2(a0, a1, v0.x); add2(a2, a3, v0.y); add2(a4, a5, v0.z); add2(a6, a7, v0.w);
    add2(a0, a1, v1.x); add2(a2, a3, v1.y); add2(a4, a5, v1.z); add2(a6, a7, v1.w);
  }
  if (j < e) {
    int g = idxAll[j];
    uint4 v = *(const uint4*)(p + (size_t)g * 64 + lq * 4);
    add2(a0, a1, v.x); add2(a2, a3, v.y); add2(a4, a5, v.z); add2(a6, a7, v.w);
  }

  // reduce across the 4 quarters
  float r[8] = {a0, a1, a2, a3, a4, a5, a6, a7};
#pragma unroll
  for (int c = 0; c < 8; ++c) {
    r[c] += __shfl_xor(r[c], 16, 64);
    r[c] += __shfl_xor(r[c], 32, 64);
  }

  float inv = 1.0f / (float)max(e - s, 1);
  if (q == 0) {                            // quarter 0 writes the row (256B)
    uint4 o;
    o.x = pack2(r[0] * inv, r[1] * inv);
    o.y = pack2(r[2] * inv, r[3] * inv);
    o.z = pack2(r[4] * inv, r[5] * inv);
    o.w = pack2(r[6] * inv, r[7] * inv);
    *(uint4*)(m2 + (size_t)n * 64 + lq * 4) = o;
  }
}

// ---------------------------------------------------------------------------
// K=256 MFMA GEMM, 128x128 tile, 4 waves (2x2), 64x64 per wave.
// ---------------------------------------------------------------------------
__global__ __launch_bounds__(256) void gemm_k256(
    const unsigned short* __restrict__ A,    // [M,256] bf16
    const unsigned short* __restrict__ BT,   // [N,256] bf16
    const float* __restrict__ bias,
    const unsigned short* __restrict__ Madd, // [M,128] bf16 or null
    void* __restrict__ outp,
    int outF32, int M, int N, int doRelu)
{
  __shared__ __attribute__((aligned(16))) unsigned short lA[128 * LDST];
  __shared__ __attribute__((aligned(16))) unsigned short lB[128 * LDST];

  const int tid = threadIdx.x;
  const int lane = tid & 63;
  const int wave = tid >> 6;
  const int waveM = wave >> 1;
  const int waveN = wave & 1;
  const int quad = lane >> 4;
  const int r16 = lane & 15;

  const int rowBase = blockIdx.x * 128;
  const int nBase = blockIdx.y * 128;

  f32x4 acc[4][4];
#pragma unroll
  for (int i = 0; i < 4; ++i)
#pragma unroll
    for (int j = 0; j < 4; ++j) acc[i][j] = (f32x4){0.f, 0.f, 0.f, 0.f};

  for (int kb = 0; kb < 4; ++kb) {
    const int kBase = kb * 64;
    if (kb) __syncthreads();

#pragma unroll
    for (int i = 0; i < 4; ++i) {
      int c = tid + i * 256;
      int row = c >> 3;
      int col8 = (c & 7) << 3;
      int grow = rowBase + row;
      uint4 v = make_uint4(0u, 0u, 0u, 0u);
      if (grow < M) v = *(const uint4*)(A + (size_t)grow * 256 + kBase + col8);
      *(uint4*)(lA + row * LDST + col8) = v;
    }
#pragma unroll
    for (int i = 0; i < 4; ++i) {
      int c = tid + i * 256;
      int row = c >> 3;
      int col8 = (c & 7) << 3;
      uint4 v = *(const uint4*)(BT + (size_t)(nBase + row) * 256 + kBase + col8);
      *(uint4*)(lB + row * LDST + col8) = v;
    }
    __syncthreads();

#pragma unroll
    for (int kk = 0; kk < 64; kk += 32) {
      short8 a[4], b[4];
#pragma unroll
      for (int mt = 0; mt < 4; ++mt)
        a[mt] = *(const short8*)(lA + (waveM * 64 + mt * 16 + r16) * LDST + kk + quad * 8);
#pragma unroll
      for (int nt = 0; nt < 4; ++nt)
        b[nt] = *(const short8*)(lB + (waveN * 64 + nt * 16 + r16) * LDST + kk + quad * 8);
#pragma unroll
      for (int mt = 0; mt < 4; ++mt)
#pragma unroll
        for (int nt = 0; nt < 4; ++nt)
          acc[mt][nt] = __builtin_amdgcn_mfma_f32_16x16x32_bf16(a[mt], b[nt], acc[mt][nt], 0, 0, 0);
    }
  }

#pragma unroll
  for (int mt = 0; mt < 4; ++mt) {
#pragma unroll
    for (int nt = 0; nt < 4; ++nt) {
      int col = nBase + waveN * 64 + nt * 16 + r16;
      float bv = bias ? bias[col] : 0.0f;
#pragma unroll
      for (int reg = 0; reg < 4; ++reg) {
        int row = rowBase + waveM * 64 + mt * 16 + quad * 4 + reg;
        if (row < M) {
          float v = acc[mt][nt][reg] + bv;
          if (Madd) v += bf2f(Madd[(size_t)row * 128 + col]);
          if (doRelu) v = fmaxf(v, 0.0f);
          if (outF32) ((float*)outp)[(size_t)row * N + col] = v;
          else ((unsigned short*)outp)[(size_t)row * N + col] = f2bf(v);
        }
      }
    }
  }
}

// ---------------------------------------------------------------------------
extern "C" void kernel_launch(void* const* d_in, const int* in_sizes, int n_in,
                              void* d_out, int out_size, void* d_ws, size_t ws_size,
                              hipStream_t stream)
{
  const float* x_user  = (const float*)d_in[0];
  const float* x_item  = (const float*)d_in[1];
  const int*   esrc    = (const int*)d_in[2];
  const int*   edst    = (const int*)d_in[3];
  const float* W_l1_ui = (const float*)d_in[4];
  const float* W_r1_ui = (const float*)d_in[5];
  const float* b_l1_ui = (const float*)d_in[6];
  const float* W_l1_iu = (const float*)d_in[7];
  const float* W_r1_iu = (const float*)d_in[8];
  const float* b_l1_iu = (const float*)d_in[9];
  const float* W_l2_ui = (const float*)d_in[10];
  const float* W_r2_ui = (const float*)d_in[11];
  const float* b_l2_ui = (const float*)d_in[12];
  const float* W_l2_iu = (const float*)d_in[13];
  const float* W_r2_iu = (const float*)d_in[14];
  const float* b_l2_iu = (const float*)d_in[15];

  const int NU = in_sizes[0] / 128;   // 200000
  const int NI = in_sizes[1] / 128;   // 100000
  const int E  = in_sizes[2];         // 500000
  const int NA = NI + NU;

  char* ws = (char*)d_ws;
  size_t off = 0;
  auto alloc = [&](size_t bytes) -> void* {
    void* p = ws + off;
    off += (bytes + 255) & ~(size_t)255;
    return p;
  };

  // --- zeroed-every-launch region ---
  int* cntAll = (int*)alloc((size_t)NA * 4);
  int* curAll = (int*)alloc((size_t)NA * 4);
  size_t zeroBytes = off;
  // --- CSR ---
  int* offAll   = (int*)alloc((size_t)(NA + 1) * 4);
  int* tileSums = (int*)alloc(256 * 4);
  int* idxAll   = (int*)alloc((size_t)2 * E * 4);
  // --- weights (bf16, transposed) ---
  unsigned short* WT1_ui  = (unsigned short*)alloc(256 * 256 * 2);
  unsigned short* WT1_iu  = (unsigned short*)alloc(256 * 256 * 2);
  unsigned short* WT2l_ui = (unsigned short*)alloc(128 * 256 * 2);
  unsigned short* WT2r_ui = (unsigned short*)alloc(128 * 256 * 2);
  unsigned short* WT2l_iu = (unsigned short*)alloc(128 * 256 * 2);
  unsigned short* WT2r_iu = (unsigned short*)alloc(128 * 256 * 2);
  // --- hidden states ---
  unsigned short* h_item = (unsigned short*)alloc((size_t)NI * 256 * 2);
  unsigned short* h_user = (unsigned short*)alloc((size_t)NU * 256 * 2);
  // --- time-shared region R (153.6 MB) ---
  char* R = (char*)alloc((size_t)NA * 256 * 2);
  // layer-1 phase:
  unsigned int* Acat_item = (unsigned int*)R;                                     // NI*128 uint
  unsigned int* Acat_user = (unsigned int*)(R + (size_t)NI * 256 * 2);            // NU*128 uint
  // layer-2 phase (Acat dead after L1 GEMMs):
  unsigned short* p_user = (unsigned short*)R;                                    // NU*128 bf16
  unsigned short* p_item = (unsigned short*)(R + (size_t)NU * 128 * 2);           // NI*128 bf16
  unsigned short* m2I    = (unsigned short*)(R + (size_t)(NU + NI) * 128 * 2);    // NI*128 bf16
  unsigned short* m2U    = (unsigned short*)(R + (size_t)(NU + 2 * NI) * 128 * 2);// NU*128 bf16

  float* out = (float*)d_out;   // [o_user (NU*128) | o_item (NI*128)] fp32

  // 1) zero counts/cursors
  hipMemsetAsync(ws, 0, zeroBytes, stream);

  // 2) weight transposes (single launch)
  build_wt_all<<<1024, 256, 0, stream>>>(
      W_l1_ui, W_r1_ui, W_l1_iu, W_r1_iu, W_l2_ui, W_r2_ui, W_l2_iu, W_r2_iu,
      WT1_ui, WT1_iu, WT2l_ui, WT2r_ui, WT2l_iu, WT2r_iu);

  // 3) CSR build: hist -> 3-pass scan -> fill
  int egrid = (E + 255) / 256;
  int nTiles = (NA + SCAN_TILE - 1) / SCAN_TILE;
  hist<<<egrid, 256, 0, stream>>>(esrc, edst, cntAll, NI, E);
  scan_p1<<<nTiles, 256, 0, stream>>>(cntAll, tileSums, NA);
  scan_p2<<<1, 256, 0, stream>>>(tileSums, nTiles, offAll + NA);
  scan_p3<<<nTiles, 256, 0, stream>>>(cntAll, tileSums, offAll, NA);
  fill_idx<<<egrid, 256, 0, stream>>>(esrc, edst, offAll, curAll, idxAll, NI, E);

  // 4) layer-1 aggregation -> Acat = [mean | x] bf16 (one launch, both types)
  build_acat<<<(NA * 64 + 255) / 256, 256, 0, stream>>>(
      x_user, x_item, idxAll, offAll, Acat_item, Acat_user, NI, NA);

  // 5) layer-1 GEMMs: h = relu(Acat @ [W_l; W_r] + b), bf16 out
  dim3 gI((NI + 127) / 128, 2), gU((NU + 127) / 128, 2);
  gemm_k256<<<gI, 256, 0, stream>>>((const unsigned short*)Acat_item, WT1_ui, b_l1_ui,
                                    nullptr, h_item, 0, NI, 256, 1);
  gemm_k256<<<gU, 256, 0, stream>>>((const unsigned short*)Acat_user, WT1_iu, b_l1_iu,
                                    nullptr, h_user, 0, NU, 256, 1);

  // 6) layer-2 left-projections: p = h @ W_l2, bf16
  dim3 pGu((NU + 127) / 128, 1), pGi((NI + 127) / 128, 1);
  gemm_k256<<<pGu, 256, 0, stream>>>(h_user, WT2l_ui, nullptr, nullptr, p_user, 0, NU, 128, 0);
  gemm_k256<<<pGi, 256, 0, stream>>>(h_item, WT2l_iu, nullptr, nullptr, p_item, 0, NI, 128, 0);

  // 7) layer-2 aggregation (one launch, both types)
  seg_mean<<<(NA * 64 + 255) / 256, 256, 0, stream>>>(
      (const unsigned int*)p_user, (const unsigned int*)p_item,
      idxAll, offAll, (unsigned int*)m2I, (unsigned int*)m2U, NI, NA);

  // 8) output GEMMs: o = relu(h @ W_r2 + m2 + b), fp32 out
  gemm_k256<<<pGi, 256, 0, stream>>>(h_item, WT2r_ui, b_l2_ui, m2I,
                                     out + (size_t)NU * 128, 1, NI, 128, 1);
  gemm_k256<<<pGu, 256, 0, stream>>>(h_user, WT2r_iu, b_l2_iu, m2U,
                                     out, 1, NU, 128, 1);
}

// Round 4
// 1000.032 us; speedup vs baseline: 1.2641x; 1.1593x over previous
//
#include <hip/hip_runtime.h>
#include <stdint.h>

typedef __attribute__((ext_vector_type(8))) short short8;
typedef __attribute__((ext_vector_type(4))) float f32x4;

#define SCAN_TILE 4096

__device__ __forceinline__ float bf2f(unsigned short u) {
  union { unsigned int i; float f; } v;
  v.i = ((unsigned int)u) << 16;
  return v.f;
}
__device__ __forceinline__ unsigned short f2bf(float f) {
  union { float f; unsigned int i; } v;
  v.f = f;
  unsigned int u = v.i;
  return (unsigned short)((u + 0x7FFFu + ((u >> 16) & 1u)) >> 16);
}
__device__ __forceinline__ unsigned int pack2(float a, float b) {
  return (unsigned int)f2bf(a) | ((unsigned int)f2bf(b) << 16);
}
__device__ __forceinline__ void add2(float& a, float& b, unsigned int v) {
  a += bf2f((unsigned short)(v & 0xffff));
  b += bf2f((unsigned short)(v >> 16));
}

// ---------------------------------------------------------------------------
// MFMA fragment layout for [rows, K=256] bf16 matrices.
// chunk = (row/16)*(256/32) + (k/32), each chunk = 1KB (64 lanes x 16B).
// lane slot within chunk = (row%16) + 16*((k%32)/8); (k%8) indexes inside 16B.
// A wave load of one fragment = uint4 at [chunk*64 + lane] -> 1KB coalesced.
// ---------------------------------------------------------------------------
__device__ __forceinline__ size_t fragS(int row, int k) {
  return ((size_t)(row >> 4) * 8 + (size_t)(k >> 5)) * 512
       + (size_t)((((row & 15) + (((k >> 3) & 3) << 4)) << 3) + (k & 7));
}

// ---------------------------------------------------------------------------
// All six weight transposes (fp32 -> bf16, [K,N] -> frag-layout [N,K-concat]).
// ---------------------------------------------------------------------------
__global__ __launch_bounds__(256) void build_wt_all(
    const float* __restrict__ Wl1ui, const float* __restrict__ Wr1ui,
    const float* __restrict__ Wl1iu, const float* __restrict__ Wr1iu,
    const float* __restrict__ Wl2ui, const float* __restrict__ Wr2ui,
    const float* __restrict__ Wl2iu, const float* __restrict__ Wr2iu,
    unsigned short* __restrict__ WT1ui, unsigned short* __restrict__ WT1iu,
    unsigned short* __restrict__ WT2lui, unsigned short* __restrict__ WT2rui,
    unsigned short* __restrict__ WT2liu, unsigned short* __restrict__ WT2riu)
{
  int idx = blockIdx.x * 256 + threadIdx.x;
  const float *W1, *W2 = nullptr;
  unsigned short* WT;
  int K1, N, rel;
  if (idx < 65536)       { W1 = Wl1ui; W2 = Wr1ui; WT = WT1ui;  K1 = 128; N = 256; rel = idx; }
  else if (idx < 131072) { W1 = Wl1iu; W2 = Wr1iu; WT = WT1iu;  K1 = 128; N = 256; rel = idx - 65536; }
  else if (idx < 163840) { W1 = Wl2ui;             WT = WT2lui; K1 = 256; N = 128; rel = idx - 131072; }
  else if (idx < 196608) { W1 = Wr2ui;             WT = WT2rui; K1 = 256; N = 128; rel = idx - 163840; }
  else if (idx < 229376) { W1 = Wl2iu;             WT = WT2liu; K1 = 256; N = 128; rel = idx - 196608; }
  else                   { W1 = Wr2iu;             WT = WT2riu; K1 = 256; N = 128; rel = idx - 229376; }
  int n = rel >> 8;        // output-col index (BT row)
  int k = rel & 255;       // concat K index
  float v = (k < K1) ? W1[(size_t)k * N + n] : W2[(size_t)(k - K1) * N + n];
  WT[fragS(n, k)] = f2bf(v);
}

// ---------------------------------------------------------------------------
// CSR build over COMBINED node space (items [0,NI), users [NI,NI+NU)).
// ---------------------------------------------------------------------------
__global__ __launch_bounds__(256) void hist(
    const int* __restrict__ esrc, const int* __restrict__ edst,
    int* __restrict__ cntAll, int NI, int E)
{
  int e = blockIdx.x * 256 + threadIdx.x;
  if (e >= E) return;
  atomicAdd(&cntAll[edst[e]], 1);
  atomicAdd(&cntAll[NI + esrc[e]], 1);
}

__global__ __launch_bounds__(256) void scan_p1(
    const int* __restrict__ cnt, int* __restrict__ tileSums, int NA)
{
  __shared__ int red[256];
  int b = blockIdx.x, t = threadIdx.x;
  int base = b * SCAN_TILE;
  int s = 0;
  for (int i = t; i < SCAN_TILE; i += 256) {
    int g = base + i;
    if (g < NA) s += cnt[g];
  }
  red[t] = s;
  __syncthreads();
  for (int d = 128; d > 0; d >>= 1) {
    if (t < d) red[t] += red[t + d];
    __syncthreads();
  }
  if (t == 0) tileSums[b] = red[0];
}

__global__ __launch_bounds__(256) void scan_p2(
    int* __restrict__ tileSums, int nTiles, int* __restrict__ offEnd)
{
  __shared__ int buf[256];
  int t = threadIdx.x;
  int v = (t < nTiles) ? tileSums[t] : 0;
  buf[t] = v;
  __syncthreads();
  for (int d = 1; d < 256; d <<= 1) {
    int x = (t >= d) ? buf[t - d] : 0;
    __syncthreads();
    buf[t] += x;
    __syncthreads();
  }
  if (t < nTiles) tileSums[t] = buf[t] - v;   // exclusive
  if (t == nTiles - 1) *offEnd = buf[t];      // grand total -> offAll[NA]
}

__global__ __launch_bounds__(256) void scan_p3(
    const int* __restrict__ cnt, const int* __restrict__ tileSums,
    int* __restrict__ off, int NA)
{
  __shared__ int red[256];
  int b = blockIdx.x, t = threadIdx.x;
  int base = b * SCAN_TILE + t * 16;
  int loc[16];
  int s = 0;
#pragma unroll
  for (int i = 0; i < 16; ++i) {
    int g = base + i;
    loc[i] = (g < NA) ? cnt[g] : 0;
    s += loc[i];
  }
  red[t] = s;
  __syncthreads();
  for (int d = 1; d < 256; d <<= 1) {
    int x = (t >= d) ? red[t - d] : 0;
    __syncthreads();
    red[t] += x;
    __syncthreads();
  }
  int run = tileSums[b] + red[t] - s;  // exclusive base for this thread
#pragma unroll
  for (int i = 0; i < 16; ++i) {
    int g = base + i;
    if (g < NA) off[g] = run;
    run += loc[i];
  }
}

__global__ __launch_bounds__(256) void fill_idx(
    const int* __restrict__ esrc, const int* __restrict__ edst,
    const int* __restrict__ offAll, int* __restrict__ curAll,
    int* __restrict__ idxAll, int NI, int E)
{
  int e = blockIdx.x * 256 + threadIdx.x;
  if (e >= E) return;
  int s = esrc[e], d = edst[e];
  int pI = offAll[d] + atomicAdd(&curAll[d], 1);
  idxAll[pI] = s;                     // item d aggregates user rows
  int pU = offAll[NI + s] + atomicAdd(&curAll[NI + s], 1);
  idxAll[pU] = d;                     // user s aggregates item rows
}

// ---------------------------------------------------------------------------
// Layer-1 aggregation, one wave per node, 2 halves x 2-unrolled row loads.
// Emits Acat[n] = [mean_neighbors | x_self] bf16 in FRAG layout (K=256).
// ---------------------------------------------------------------------------
__global__ __launch_bounds__(256) void build_acat(
    const float* __restrict__ xu, const float* __restrict__ xi,
    const int* __restrict__ idxAll, const int* __restrict__ offAll,
    unsigned short* __restrict__ AcatI, unsigned short* __restrict__ AcatU,
    int NI, int NA)
{
  int w = (blockIdx.x * 256 + threadIdx.x) >> 6;
  if (w >= NA) return;
  int l = threadIdx.x & 63;
  int h = l >> 5;                          // half id (0/1)
  int lh = l & 31;                         // lane within half
  bool isItem = (w < NI);
  const float* xo = isItem ? xu : xi;      // neighbor features
  const float* xs = isItem ? xi : xu;      // self features
  unsigned short* Acat = isItem ? AcatI : AcatU;
  int n = isItem ? w : (w - NI);
  int s = offAll[w], e = offAll[w + 1];

  // hoist self-feature load (upper half only) so it overlaps the gather loop
  f32x4 xv = (f32x4){0.f, 0.f, 0.f, 0.f};
  if (h) xv = *(const f32x4*)(xs + (size_t)n * 128 + lh * 4);

  f32x4 acc = (f32x4){0.f, 0.f, 0.f, 0.f};
  int j = s + h;                           // this half's neighbor stream (stride 2)
  for (; j + 2 < e; j += 4) {              // 2 rows per half in flight
    int g0 = idxAll[j];
    int g1 = idxAll[j + 2];
    f32x4 v0 = *(const f32x4*)(xo + (size_t)g0 * 128 + lh * 4);
    f32x4 v1 = *(const f32x4*)(xo + (size_t)g1 * 128 + lh * 4);
    acc += v0 + v1;
  }
  if (j < e) {
    int g = idxAll[j];
    acc += *(const f32x4*)(xo + (size_t)g * 128 + lh * 4);
  }

  // combine halves: every lane ends with full sum of its 4 elements
#pragma unroll
  for (int c = 0; c < 4; ++c)
    acc[c] += __shfl_xor(acc[c], 32, 64);

  float inv = 1.0f / (float)max(e - s, 1);
  // each lane owns 4 consecutive K-elements: kb..kb+3
  int kb = (h ? 128 : 0) + lh * 4;
  float x0, x1, x2, x3;
  if (h) { x0 = xv[0]; x1 = xv[1]; x2 = xv[2]; x3 = xv[3]; }
  else   { x0 = acc[0] * inv; x1 = acc[1] * inv; x2 = acc[2] * inv; x3 = acc[3] * inv; }
  uint2 o;
  o.x = pack2(x0, x1);
  o.y = pack2(x2, x3);
  *(uint2*)(Acat + fragS(n, kb)) = o;
}

// ---------------------------------------------------------------------------
// Layer-2 aggregation: 4x 16-lane quarters, full 256B row per quarter, 2x
// unrolled. p is ROW-MAJOR [M,128] bf16; m2 row-major bf16 out.
// ---------------------------------------------------------------------------
__global__ __launch_bounds__(256) void seg_mean(
    const unsigned int* __restrict__ pU, const unsigned int* __restrict__ pI,
    const int* __restrict__ idxAll, const int* __restrict__ offAll,
    unsigned int* __restrict__ m2I, unsigned int* __restrict__ m2U,
    int NI, int NA)
{
  int w = (blockIdx.x * 256 + threadIdx.x) >> 6;
  if (w >= NA) return;
  int l = threadIdx.x & 63;
  int q = l >> 4;                          // quarter id (0..3)
  int lq = l & 15;                         // lane within quarter
  bool isItem = (w < NI);
  const unsigned int* p = isItem ? pU : pI;
  unsigned int* m2 = isItem ? m2I : m2U;
  int n = isItem ? w : (w - NI);
  int s = offAll[w], e = offAll[w + 1];

  float a0 = 0.f, a1 = 0.f, a2 = 0.f, a3 = 0.f,
        a4 = 0.f, a5 = 0.f, a6 = 0.f, a7 = 0.f;

  int j = s + q;                           // this quarter's stream (stride 4)
  for (; j + 4 < e; j += 8) {              // 2 rows per quarter in flight
    int g0 = idxAll[j];
    int g1 = idxAll[j + 4];
    uint4 v0 = *(const uint4*)(p + (size_t)g0 * 64 + lq * 4);
    uint4 v1 = *(const uint4*)(p + (size_t)g1 * 64 + lq * 4);
    add2(a0, a1, v0.x); add2(a2, a3, v0.y); add2(a4, a5, v0.z); add2(a6, a7, v0.w);
    add2(a0, a1, v1.x); add2(a2, a3, v1.y); add2(a4, a5, v1.z); add2(a6, a7, v1.w);
  }
  if (j < e) {
    int g = idxAll[j];
    uint4 v = *(const uint4*)(p + (size_t)g * 64 + lq * 4);
    add2(a0, a1, v.x); add2(a2, a3, v.y); add2(a4, a5, v.z); add2(a6, a7, v.w);
  }

  float r[8] = {a0, a1, a2, a3, a4, a5, a6, a7};
#pragma unroll
  for (int c = 0; c < 8; ++c) {
    r[c] += __shfl_xor(r[c], 16, 64);
    r[c] += __shfl_xor(r[c], 32, 64);
  }

  float inv = 1.0f / (float)max(e - s, 1);
  if (q == 0) {
    uint4 o;
    o.x = pack2(r[0] * inv, r[1] * inv);
    o.y = pack2(r[2] * inv, r[3] * inv);
    o.z = pack2(r[4] * inv, r[5] * inv);
    o.w = pack2(r[6] * inv, r[7] * inv);
    *(uint4*)(m2 + (size_t)n * 64 + lq * 4) = o;
  }
}

// ---------------------------------------------------------------------------
// Barrier-free "flat" GEMM for tall-skinny shapes (K=256).
// A and B are in frag layout; every fragment load is a fully-coalesced 1KB
// uint4 wave load. No LDS, no __syncthreads -> pure ILP/TLP latency hiding.
// MFMA operands SWAPPED (mfma(b, a, acc)) so D is transposed: lane holds
// row = lane&15, cols = quad*4 + reg (4 consecutive) -> vectorized stores.
// Block = 128 rows x 128 cols (grid.y = N/128), 4 waves 2x2, 64x64 per wave.
// Epilogue modes: +bias, +Madd (row-major [M,128] bf16), relu;
// out: fp32 row-major | bf16 row-major | bf16 frag layout.
// ---------------------------------------------------------------------------
__global__ __launch_bounds__(256, 3) void gemm_flat(
    const unsigned short* __restrict__ Afrag,  // [Mpad,256] frag
    const unsigned short* __restrict__ Bfrag,  // [N,256] frag
    const float* __restrict__ bias,
    const unsigned short* __restrict__ Madd,   // [M,128] row-major or null
    void* __restrict__ outp,
    int outF32, int outFrag, int M, int N, int doRelu)
{
  const int lane = threadIdx.x & 63;
  const int wave = threadIdx.x >> 6;
  const int m0 = blockIdx.x * 128 + (wave >> 1) * 64;  // wave's first row
  const int n0 = blockIdx.y * 128 + (wave & 1) * 64;   // wave's first col
  const int r16 = lane & 15;
  const int quad = lane >> 4;

  const uint4* A = (const uint4*)Afrag;
  const uint4* B = (const uint4*)Bfrag;
  // uint4 index of fragment (rowgrp, k0) = ((rowgrp)*8 + k0)*64 + lane
  const size_t aB = (size_t)(m0 >> 4) * 512 + lane;
  const size_t bB = (size_t)(n0 >> 4) * 512 + lane;

  f32x4 acc[4][4];
#pragma unroll
  for (int i = 0; i < 4; ++i)
#pragma unroll
    for (int j = 0; j < 4; ++j) acc[i][j] = (f32x4){0.f, 0.f, 0.f, 0.f};

#pragma unroll
  for (int k0 = 0; k0 < 8; ++k0) {
    short8 av[4], bv[4];
#pragma unroll
    for (int g = 0; g < 4; ++g) {
      uint4 ta = A[aB + (size_t)(g * 8 + k0) * 64];
      uint4 tb = B[bB + (size_t)(g * 8 + k0) * 64];
      av[g] = *(const short8*)&ta;
      bv[g] = *(const short8*)&tb;
    }
#pragma unroll
    for (int mg = 0; mg < 4; ++mg)
#pragma unroll
      for (int ng = 0; ng < 4; ++ng)
        acc[mg][ng] = __builtin_amdgcn_mfma_f32_16x16x32_bf16(bv[ng], av[mg], acc[mg][ng], 0, 0, 0);
  }

#pragma unroll
  for (int mg = 0; mg < 4; ++mg) {
    int row = m0 + mg * 16 + r16;
    if (row < M) {
#pragma unroll
      for (int ng = 0; ng < 4; ++ng) {
        int col = n0 + ng * 16 + quad * 4;   // 4 consecutive cols in regs
        f32x4 v = acc[mg][ng];
        if (bias) {
          f32x4 b4 = *(const f32x4*)(bias + col);
          v += b4;
        }
        if (Madd) {
          uint2 md = *(const uint2*)(Madd + (size_t)row * 128 + col);
          v[0] += bf2f((unsigned short)(md.x & 0xffff));
          v[1] += bf2f((unsigned short)(md.x >> 16));
          v[2] += bf2f((unsigned short)(md.y & 0xffff));
          v[3] += bf2f((unsigned short)(md.y >> 16));
        }
        if (doRelu) {
          v[0] = fmaxf(v[0], 0.0f); v[1] = fmaxf(v[1], 0.0f);
          v[2] = fmaxf(v[2], 0.0f); v[3] = fmaxf(v[3], 0.0f);
        }
        if (outF32) {
          *(f32x4*)((float*)outp + (size_t)row * N + col) = v;
        } else {
          uint2 o;
          o.x = pack2(v[0], v[1]);
          o.y = pack2(v[2], v[3]);
          if (outFrag) *(uint2*)((unsigned short*)outp + fragS(row, col)) = o;
          else         *(uint2*)((unsigned short*)outp + (size_t)row * N + col) = o;
        }
      }
    }
  }
}

// ---------------------------------------------------------------------------
extern "C" void kernel_launch(void* const* d_in, const int* in_sizes, int n_in,
                              void* d_out, int out_size, void* d_ws, size_t ws_size,
                              hipStream_t stream)
{
  const float* x_user  = (const float*)d_in[0];
  const float* x_item  = (const float*)d_in[1];
  const int*   esrc    = (const int*)d_in[2];
  const int*   edst    = (const int*)d_in[3];
  const float* W_l1_ui = (const float*)d_in[4];
  const float* W_r1_ui = (const float*)d_in[5];
  const float* b_l1_ui = (const float*)d_in[6];
  const float* W_l1_iu = (const float*)d_in[7];
  const float* W_r1_iu = (const float*)d_in[8];
  const float* b_l1_iu = (const float*)d_in[9];
  const float* W_l2_ui = (const float*)d_in[10];
  const float* W_r2_ui = (const float*)d_in[11];
  const float* b_l2_ui = (const float*)d_in[12];
  const float* W_l2_iu = (const float*)d_in[13];
  const float* W_r2_iu = (const float*)d_in[14];
  const float* b_l2_iu = (const float*)d_in[15];

  const int NU = in_sizes[0] / 128;   // 200000
  const int NI = in_sizes[1] / 128;   // 100000
  const int E  = in_sizes[2];         // 500000
  const int NA = NI + NU;
  const int MI = ((NI + 127) / 128) * 128;   // padded row counts (tail blocks
  const int MU = ((NU + 127) / 128) * 128;   // read A past M; keep in-buffer)

  char* ws = (char*)d_ws;
  size_t off = 0;
  auto alloc = [&](size_t bytes) -> void* {
    void* p = ws + off;
    off += (bytes + 255) & ~(size_t)255;
    return p;
  };

  // --- zeroed-every-launch region ---
  int* cntAll = (int*)alloc((size_t)NA * 4);
  int* curAll = (int*)alloc((size_t)NA * 4);
  size_t zeroBytes = off;
  // --- CSR ---
  int* offAll   = (int*)alloc((size_t)(NA + 1) * 4);
  int* tileSums = (int*)alloc(256 * 4);
  int* idxAll   = (int*)alloc((size_t)2 * E * 4);
  // --- weights (bf16, frag layout) ---
  unsigned short* WT1_ui  = (unsigned short*)alloc(256 * 256 * 2);
  unsigned short* WT1_iu  = (unsigned short*)alloc(256 * 256 * 2);
  unsigned short* WT2l_ui = (unsigned short*)alloc(128 * 256 * 2);
  unsigned short* WT2r_ui = (unsigned short*)alloc(128 * 256 * 2);
  unsigned short* WT2l_iu = (unsigned short*)alloc(128 * 256 * 2);
  unsigned short* WT2r_iu = (unsigned short*)alloc(128 * 256 * 2);
  // --- hidden states (frag layout, padded rows) ---
  unsigned short* h_item = (unsigned short*)alloc((size_t)MI * 256 * 2);
  unsigned short* h_user = (unsigned short*)alloc((size_t)MU * 256 * 2);
  // --- time-shared region R ---
  char* R = (char*)alloc((size_t)(MI + MU) * 256 * 2);
  // layer-1 phase (frag Acat, padded rows):
  unsigned short* Acat_item = (unsigned short*)R;                         // MI*256 bf16
  unsigned short* Acat_user = (unsigned short*)(R + (size_t)MI * 256 * 2);// MU*256 bf16
  // layer-2 phase (Acat dead after L1 GEMMs); p/m2 ROW-MAJOR:
  unsigned short* p_user = (unsigned short*)R;                                    // NU*128 bf16
  unsigned short* p_item = (unsigned short*)(R + (size_t)NU * 128 * 2);           // NI*128 bf16
  unsigned short* m2I    = (unsigned short*)(R + (size_t)(NU + NI) * 128 * 2);    // NI*128 bf16
  unsigned short* m2U    = (unsigned short*)(R + (size_t)(NU + 2 * NI) * 128 * 2);// NU*128 bf16

  float* out = (float*)d_out;   // [o_user (NU*128) | o_item (NI*128)] fp32

  // 1) zero counts/cursors
  hipMemsetAsync(ws, 0, zeroBytes, stream);

  // 2) weight transposes -> frag layout (single launch)
  build_wt_all<<<1024, 256, 0, stream>>>(
      W_l1_ui, W_r1_ui, W_l1_iu, W_r1_iu, W_l2_ui, W_r2_ui, W_l2_iu, W_r2_iu,
      WT1_ui, WT1_iu, WT2l_ui, WT2r_ui, WT2l_iu, WT2r_iu);

  // 3) CSR build: hist -> 3-pass scan -> fill
  int egrid = (E + 255) / 256;
  int nTiles = (NA + SCAN_TILE - 1) / SCAN_TILE;
  hist<<<egrid, 256, 0, stream>>>(esrc, edst, cntAll, NI, E);
  scan_p1<<<nTiles, 256, 0, stream>>>(cntAll, tileSums, NA);
  scan_p2<<<1, 256, 0, stream>>>(tileSums, nTiles, offAll + NA);
  scan_p3<<<nTiles, 256, 0, stream>>>(cntAll, tileSums, offAll, NA);
  fill_idx<<<egrid, 256, 0, stream>>>(esrc, edst, offAll, curAll, idxAll, NI, E);

  // 4) layer-1 aggregation -> Acat = [mean | x] bf16 frag layout
  build_acat<<<(NA * 64 + 255) / 256, 256, 0, stream>>>(
      x_user, x_item, idxAll, offAll, Acat_item, Acat_user, NI, NA);

  // 5) layer-1 GEMMs: h = relu(Acat @ [W_l; W_r] + b), frag bf16 out
  dim3 gI(MI / 128, 2), gU(MU / 128, 2);
  gemm_flat<<<gI, 256, 0, stream>>>(Acat_item, WT1_ui, b_l1_ui, nullptr,
                                    h_item, 0, 1, NI, 256, 1);
  gemm_flat<<<gU, 256, 0, stream>>>(Acat_user, WT1_iu, b_l1_iu, nullptr,
                                    h_user, 0, 1, NU, 256, 1);

  // 6) layer-2 left-projections: p = h @ W_l2, row-major bf16
  dim3 pGu(MU / 128, 1), pGi(MI / 128, 1);
  gemm_flat<<<pGu, 256, 0, stream>>>(h_user, WT2l_ui, nullptr, nullptr,
                                     p_user, 0, 0, NU, 128, 0);
  gemm_flat<<<pGi, 256, 0, stream>>>(h_item, WT2l_iu, nullptr, nullptr,
                                     p_item, 0, 0, NI, 128, 0);

  // 7) layer-2 aggregation (one launch, both types)
  seg_mean<<<(NA * 64 + 255) / 256, 256, 0, stream>>>(
      (const unsigned int*)p_user, (const unsigned int*)p_item,
      idxAll, offAll, (unsigned int*)m2I, (unsigned int*)m2U, NI, NA);

  // 8) output GEMMs: o = relu(h @ W_r2 + m2 + b), fp32 row-major out
  gemm_flat<<<pGi, 256, 0, stream>>>(h_item, WT2r_ui, b_l2_ui, m2I,
                                     out + (size_t)NU * 128, 1, 0, NI, 128, 1);
  gemm_flat<<<pGu, 256, 0, stream>>>(h_user, WT2r_iu, b_l2_iu, m2U,
                                     out, 1, 0, NU, 128, 1);
}

// Round 5
// 854.513 us; speedup vs baseline: 1.4793x; 1.1703x over previous
//
#include <hip/hip_runtime.h>
#include <stdint.h>

typedef __attribute__((ext_vector_type(8))) short short8;
typedef __attribute__((ext_vector_type(4))) float f32x4;

#define SCAN_TILE 4096

__device__ __forceinline__ float bf2f(unsigned short u) {
  union { unsigned int i; float f; } v;
  v.i = ((unsigned int)u) << 16;
  return v.f;
}
__device__ __forceinline__ unsigned short f2bf(float f) {
  union { float f; unsigned int i; } v;
  v.f = f;
  unsigned int u = v.i;
  return (unsigned short)((u + 0x7FFFu + ((u >> 16) & 1u)) >> 16);
}
__device__ __forceinline__ unsigned int pack2(float a, float b) {
  return (unsigned int)f2bf(a) | ((unsigned int)f2bf(b) << 16);
}
__device__ __forceinline__ void add2(float& a, float& b, unsigned int v) {
  a += bf2f((unsigned short)(v & 0xffff));
  b += bf2f((unsigned short)(v >> 16));
}

// ---------------------------------------------------------------------------
// MFMA fragment layout for [rows, K=128] bf16 matrices.
// chunk = (row/16)*4 + (k/32), each chunk = 1KB (64 lanes x 16B).
// slot within chunk = (row%16) + 16*((k%32)/8); (k%8) indexes inside 16B.
// A wave load of one fragment = uint4 at [chunk*64 + lane] -> 1KB coalesced.
// ---------------------------------------------------------------------------
__device__ __forceinline__ size_t fragS128(int row, int k) {
  return ((size_t)(row >> 4) * 4 + (size_t)(k >> 5)) * 512
       + (size_t)((((row & 15) + (((k >> 3) & 3) << 4)) << 3) + (k & 7));
}

// ---------------------------------------------------------------------------
// Weight transposes (fp32 -> bf16, [K,N] -> frag128 split lo/hi) in one launch.
// K=256 concat [Wl;Wr] (layer1) or single K=256 W (layer2, W2 = W+128*N).
// ---------------------------------------------------------------------------
__global__ __launch_bounds__(256) void build_wt_all(
    const float* __restrict__ Wl1ui, const float* __restrict__ Wr1ui,
    const float* __restrict__ Wl1iu, const float* __restrict__ Wr1iu,
    const float* __restrict__ Wl2ui, const float* __restrict__ Wr2ui,
    const float* __restrict__ Wl2iu, const float* __restrict__ Wr2iu,
    unsigned short* __restrict__ T1ui_l, unsigned short* __restrict__ T1ui_h,
    unsigned short* __restrict__ T1iu_l, unsigned short* __restrict__ T1iu_h,
    unsigned short* __restrict__ T2lui_l, unsigned short* __restrict__ T2lui_h,
    unsigned short* __restrict__ T2rui_l, unsigned short* __restrict__ T2rui_h,
    unsigned short* __restrict__ T2liu_l, unsigned short* __restrict__ T2liu_h,
    unsigned short* __restrict__ T2riu_l, unsigned short* __restrict__ T2riu_h)
{
  int idx = blockIdx.x * 256 + threadIdx.x;
  const float *W1, *W2;
  unsigned short *lo, *hi;
  int N, rel;
  if (idx < 65536)       { W1 = Wl1ui; W2 = Wr1ui;          lo = T1ui_l;  hi = T1ui_h;  N = 256; rel = idx; }
  else if (idx < 131072) { W1 = Wl1iu; W2 = Wr1iu;          lo = T1iu_l;  hi = T1iu_h;  N = 256; rel = idx - 65536; }
  else if (idx < 163840) { W1 = Wl2ui; W2 = Wl2ui + 128*128; lo = T2lui_l; hi = T2lui_h; N = 128; rel = idx - 131072; }
  else if (idx < 196608) { W1 = Wr2ui; W2 = Wr2ui + 128*128; lo = T2rui_l; hi = T2rui_h; N = 128; rel = idx - 163840; }
  else if (idx < 229376) { W1 = Wl2iu; W2 = Wl2iu + 128*128; lo = T2liu_l; hi = T2liu_h; N = 128; rel = idx - 196608; }
  else                   { W1 = Wr2iu; W2 = Wr2iu + 128*128; lo = T2riu_l; hi = T2riu_h; N = 128; rel = idx - 229376; }
  int n = rel >> 8;        // output-col index (B-frag row)
  int k = rel & 255;       // concat K index
  float v = (k < 128) ? W1[(size_t)k * N + n] : W2[(size_t)(k - 128) * N + n];
  if (k < 128) lo[fragS128(n, k)] = f2bf(v);
  else         hi[fragS128(n, k - 128)] = f2bf(v);
}

// ---------------------------------------------------------------------------
// Streaming fp32 -> bf16 frag128 conversion of self-features (x_item, x_user).
// Thread <-> output 16B unit: writes are perfectly contiguous/coalesced.
// Pad rows (>= M) are zero-filled.
// ---------------------------------------------------------------------------
__global__ __launch_bounds__(256) void conv_x(
    const float* __restrict__ xu, const float* __restrict__ xi,
    uint4* __restrict__ XfI, uint4* __restrict__ XfU,
    int NI, int NU, int MI, int MU)
{
  int u = blockIdx.x * 256 + threadIdx.x;
  int unitsI = MI * 16;
  const float* x; uint4* Xf; int M; int rel;
  if (u < unitsI) { x = xi; Xf = XfI; M = NI; rel = u; }
  else {
    rel = u - unitsI;
    if (rel >= MU * 16) return;
    x = xu; Xf = XfU; M = NU;
  }
  int c = rel >> 6;                      // chunk
  int s = rel & 63;                      // 16B slot in chunk
  int row = ((c >> 2) << 4) + (s & 15);
  int k = ((c & 3) << 5) + ((s >> 4) << 3);
  uint4 o = make_uint4(0u, 0u, 0u, 0u);
  if (row < M) {
    f32x4 a = *(const f32x4*)(x + (size_t)row * 128 + k);
    f32x4 b = *(const f32x4*)(x + (size_t)row * 128 + k + 4);
    o.x = pack2(a[0], a[1]); o.y = pack2(a[2], a[3]);
    o.z = pack2(b[0], b[1]); o.w = pack2(b[2], b[3]);
  }
  Xf[rel] = o;
}

// ---------------------------------------------------------------------------
// CSR build over COMBINED node space (items [0,NI), users [NI,NI+NU)).
// ---------------------------------------------------------------------------
__global__ __launch_bounds__(256) void hist(
    const int* __restrict__ esrc, const int* __restrict__ edst,
    int* __restrict__ cntAll, int NI, int E)
{
  int e = blockIdx.x * 256 + threadIdx.x;
  if (e >= E) return;
  atomicAdd(&cntAll[edst[e]], 1);
  atomicAdd(&cntAll[NI + esrc[e]], 1);
}

__global__ __launch_bounds__(256) void scan_p1(
    const int* __restrict__ cnt, int* __restrict__ tileSums, int NA)
{
  __shared__ int red[256];
  int b = blockIdx.x, t = threadIdx.x;
  int base = b * SCAN_TILE;
  int s = 0;
  for (int i = t; i < SCAN_TILE; i += 256) {
    int g = base + i;
    if (g < NA) s += cnt[g];
  }
  red[t] = s;
  __syncthreads();
  for (int d = 128; d > 0; d >>= 1) {
    if (t < d) red[t] += red[t + d];
    __syncthreads();
  }
  if (t == 0) tileSums[b] = red[0];
}

__global__ __launch_bounds__(256) void scan_p2(
    int* __restrict__ tileSums, int nTiles, int* __restrict__ offEnd)
{
  __shared__ int buf[256];
  int t = threadIdx.x;
  int v = (t < nTiles) ? tileSums[t] : 0;
  buf[t] = v;
  __syncthreads();
  for (int d = 1; d < 256; d <<= 1) {
    int x = (t >= d) ? buf[t - d] : 0;
    __syncthreads();
    buf[t] += x;
    __syncthreads();
  }
  if (t < nTiles) tileSums[t] = buf[t] - v;   // exclusive
  if (t == nTiles - 1) *offEnd = buf[t];      // grand total -> offAll[NA]
}

__global__ __launch_bounds__(256) void scan_p3(
    const int* __restrict__ cnt, const int* __restrict__ tileSums,
    int* __restrict__ off, int NA)
{
  __shared__ int red[256];
  int b = blockIdx.x, t = threadIdx.x;
  int base = b * SCAN_TILE + t * 16;
  int loc[16];
  int s = 0;
#pragma unroll
  for (int i = 0; i < 16; ++i) {
    int g = base + i;
    loc[i] = (g < NA) ? cnt[g] : 0;
    s += loc[i];
  }
  red[t] = s;
  __syncthreads();
  for (int d = 1; d < 256; d <<= 1) {
    int x = (t >= d) ? red[t - d] : 0;
    __syncthreads();
    red[t] += x;
    __syncthreads();
  }
  int run = tileSums[b] + red[t] - s;  // exclusive base for this thread
#pragma unroll
  for (int i = 0; i < 16; ++i) {
    int g = base + i;
    if (g < NA) off[g] = run;
    run += loc[i];
  }
}

__global__ __launch_bounds__(256) void fill_idx(
    const int* __restrict__ esrc, const int* __restrict__ edst,
    const int* __restrict__ offAll, int* __restrict__ curAll,
    int* __restrict__ idxAll, int NI, int E)
{
  int e = blockIdx.x * 256 + threadIdx.x;
  if (e >= E) return;
  int s = esrc[e], d = edst[e];
  int pI = offAll[d] + atomicAdd(&curAll[d], 1);
  idxAll[pI] = s;                     // item d aggregates user rows
  int pU = offAll[NI + s] + atomicAdd(&curAll[NI + s], 1);
  idxAll[pU] = d;                     // user s aggregates item rows
}

// ---------------------------------------------------------------------------
// Layer-1 neighbor mean, one 32-lane HALF per node (2 nodes/wave, two
// independent chains, no shuffles). Full 512B fp32 row per half via float4,
// 2x-unrolled. Emits mean bf16 in frag128 layout.
// ---------------------------------------------------------------------------
__global__ __launch_bounds__(256) void build_mean(
    const float* __restrict__ xu, const float* __restrict__ xi,
    const int* __restrict__ idxAll, const int* __restrict__ offAll,
    unsigned short* __restrict__ MfI, unsigned short* __restrict__ MfU,
    int NI, int NA)
{
  int w2 = (blockIdx.x * 256 + threadIdx.x) >> 6;   // wave id
  int l = threadIdx.x & 63;
  int h = l >> 5;                          // half id (0/1)
  int lh = l & 31;                         // lane within half
  int node = w2 * 2 + h;
  if (node >= NA) return;
  bool isItem = (node < NI);
  const float* xo = isItem ? xu : xi;      // neighbor features
  unsigned short* Mf = isItem ? MfI : MfU;
  int n = isItem ? node : (node - NI);
  int s = offAll[node], e = offAll[node + 1];

  f32x4 acc = (f32x4){0.f, 0.f, 0.f, 0.f};
  int j = s;
  for (; j + 1 < e; j += 2) {              // 2 rows in flight per half
    int g0 = idxAll[j];
    int g1 = idxAll[j + 1];
    f32x4 v0 = *(const f32x4*)(xo + (size_t)g0 * 128 + lh * 4);
    f32x4 v1 = *(const f32x4*)(xo + (size_t)g1 * 128 + lh * 4);
    acc += v0 + v1;
  }
  if (j < e) {
    int g = idxAll[j];
    acc += *(const f32x4*)(xo + (size_t)g * 128 + lh * 4);
  }

  float inv = 1.0f / (float)max(e - s, 1);
  uint2 o;
  o.x = pack2(acc[0] * inv, acc[1] * inv);
  o.y = pack2(acc[2] * inv, acc[3] * inv);
  *(uint2*)(Mf + fragS128(n, lh * 4)) = o;
}

// ---------------------------------------------------------------------------
// Layer-2 aggregation: one 16-lane QUARTER per node (4 nodes/wave, no
// shuffles). Full 256B bf16 row per quarter via uint4, 2x-unrolled.
// m2 row-major bf16 out (coalesced uint4 store).
// ---------------------------------------------------------------------------
__global__ __launch_bounds__(256) void seg_mean(
    const unsigned int* __restrict__ pU, const unsigned int* __restrict__ pI,
    const int* __restrict__ idxAll, const int* __restrict__ offAll,
    unsigned int* __restrict__ m2I, unsigned int* __restrict__ m2U,
    int NI, int NA)
{
  int w4 = (blockIdx.x * 256 + threadIdx.x) >> 6;
  int l = threadIdx.x & 63;
  int q = l >> 4;                          // quarter id (0..3)
  int lq = l & 15;                         // lane within quarter
  int node = w4 * 4 + q;
  if (node >= NA) return;
  bool isItem = (node < NI);
  const unsigned int* p = isItem ? pU : pI;
  unsigned int* m2 = isItem ? m2I : m2U;
  int n = isItem ? node : (node - NI);
  int s = offAll[node], e = offAll[node + 1];

  float a0 = 0.f, a1 = 0.f, a2 = 0.f, a3 = 0.f,
        a4 = 0.f, a5 = 0.f, a6 = 0.f, a7 = 0.f;

  int j = s;
  for (; j + 1 < e; j += 2) {              // 2 rows in flight per quarter
    int g0 = idxAll[j];
    int g1 = idxAll[j + 1];
    uint4 v0 = *(const uint4*)(p + (size_t)g0 * 64 + lq * 4);
    uint4 v1 = *(const uint4*)(p + (size_t)g1 * 64 + lq * 4);
    add2(a0, a1, v0.x); add2(a2, a3, v0.y); add2(a4, a5, v0.z); add2(a6, a7, v0.w);
    add2(a0, a1, v1.x); add2(a2, a3, v1.y); add2(a4, a5, v1.z); add2(a6, a7, v1.w);
  }
  if (j < e) {
    int g = idxAll[j];
    uint4 v = *(const uint4*)(p + (size_t)g * 64 + lq * 4);
    add2(a0, a1, v.x); add2(a2, a3, v.y); add2(a4, a5, v.z); add2(a6, a7, v.w);
  }

  float inv = 1.0f / (float)max(e - s, 1);
  uint4 o;
  o.x = pack2(a0 * inv, a1 * inv);
  o.y = pack2(a2 * inv, a3 * inv);
  o.z = pack2(a4 * inv, a5 * inv);
  o.w = pack2(a6 * inv, a7 * inv);
  *(uint4*)(m2 + (size_t)n * 64 + lq * 4) = o;
}

// ---------------------------------------------------------------------------
// Barrier-free flat GEMM, K = 128 + 128 (split frag128 operands).
// No LDS, no __syncthreads; every fragment load = coalesced 1KB wave load.
// MFMA operands swapped (mfma(b, a, acc)) -> lane holds row=lane&15,
// cols quad*4+reg (4 consecutive) -> vectorized stores.
// Block = 128 rows x 128 cols, 4 waves 2x2, 64x64 per wave.
// out: fp32 row-major | bf16 row-major | bf16 frag128 split (outp/outHi).
// ---------------------------------------------------------------------------
__global__ __launch_bounds__(256, 3) void gemm_flat(
    const unsigned short* __restrict__ Alo, const unsigned short* __restrict__ Ahi,
    const unsigned short* __restrict__ Blo, const unsigned short* __restrict__ Bhi,
    const float* __restrict__ bias,
    const unsigned short* __restrict__ Madd,   // [M,128] row-major or null
    void* __restrict__ outp, unsigned short* __restrict__ outHi,
    int outF32, int outFrag, int M, int N, int doRelu)
{
  const int lane = threadIdx.x & 63;
  const int wave = threadIdx.x >> 6;
  const int m0 = blockIdx.x * 128 + (wave >> 1) * 64;  // wave's first row
  const int n0 = blockIdx.y * 128 + (wave & 1) * 64;   // wave's first col
  const int r16 = lane & 15;
  const int quad = lane >> 4;

  const uint4* AL = (const uint4*)Alo;
  const uint4* AH = (const uint4*)Ahi;
  const uint4* BL = (const uint4*)Blo;
  const uint4* BH = (const uint4*)Bhi;
  // frag128: 4 chunks x 64 uint4 per 16-row group
  const size_t aB = (size_t)(m0 >> 4) * 256 + lane;
  const size_t bB = (size_t)(n0 >> 4) * 256 + lane;

  f32x4 acc[4][4];
#pragma unroll
  for (int i = 0; i < 4; ++i)
#pragma unroll
    for (int j = 0; j < 4; ++j) acc[i][j] = (f32x4){0.f, 0.f, 0.f, 0.f};

#pragma unroll
  for (int k0 = 0; k0 < 4; ++k0) {
    short8 av[4], bv[4];
#pragma unroll
    for (int g = 0; g < 4; ++g) {
      uint4 ta = AL[aB + (size_t)(g * 4 + k0) * 64];
      uint4 tb = BL[bB + (size_t)(g * 4 + k0) * 64];
      av[g] = *(const short8*)&ta;
      bv[g] = *(const short8*)&tb;
    }
#pragma unroll
    for (int mg = 0; mg < 4; ++mg)
#pragma unroll
      for (int ng = 0; ng < 4; ++ng)
        acc[mg][ng] = __builtin_amdgcn_mfma_f32_16x16x32_bf16(bv[ng], av[mg], acc[mg][ng], 0, 0, 0);
  }
#pragma unroll
  for (int k0 = 0; k0 < 4; ++k0) {
    short8 av[4], bv[4];
#pragma unroll
    for (int g = 0; g < 4; ++g) {
      uint4 ta = AH[aB + (size_t)(g * 4 + k0) * 64];
      uint4 tb = BH[bB + (size_t)(g * 4 + k0) * 64];
      av[g] = *(const short8*)&ta;
      bv[g] = *(const short8*)&tb;
    }
#pragma unroll
    for (int mg = 0; mg < 4; ++mg)
#pragma unroll
      for (int ng = 0; ng < 4; ++ng)
        acc[mg][ng] = __builtin_amdgcn_mfma_f32_16x16x32_bf16(bv[ng], av[mg], acc[mg][ng], 0, 0, 0);
  }

#pragma unroll
  for (int mg = 0; mg < 4; ++mg) {
    int row = m0 + mg * 16 + r16;
    if (row < M) {
#pragma unroll
      for (int ng = 0; ng < 4; ++ng) {
        int col = n0 + ng * 16 + quad * 4;   // 4 consecutive cols in regs
        f32x4 v = acc[mg][ng];
        if (bias) {
          f32x4 b4 = *(const f32x4*)(bias + col);
          v += b4;
        }
        if (Madd) {
          uint2 md = *(const uint2*)(Madd + (size_t)row * 128 + col);
          v[0] += bf2f((unsigned short)(md.x & 0xffff));
          v[1] += bf2f((unsigned short)(md.x >> 16));
          v[2] += bf2f((unsigned short)(md.y & 0xffff));
          v[3] += bf2f((unsigned short)(md.y >> 16));
        }
        if (doRelu) {
          v[0] = fmaxf(v[0], 0.0f); v[1] = fmaxf(v[1], 0.0f);
          v[2] = fmaxf(v[2], 0.0f); v[3] = fmaxf(v[3], 0.0f);
        }
        if (outF32) {
          *(f32x4*)((float*)outp + (size_t)row * N + col) = v;
        } else {
          uint2 o;
          o.x = pack2(v[0], v[1]);
          o.y = pack2(v[2], v[3]);
          if (outFrag) {
            if (col < 128) *(uint2*)((unsigned short*)outp + fragS128(row, col)) = o;
            else           *(uint2*)(outHi + fragS128(row, col - 128)) = o;
          } else {
            *(uint2*)((unsigned short*)outp + (size_t)row * N + col) = o;
          }
        }
      }
    }
  }
}

// ---------------------------------------------------------------------------
extern "C" void kernel_launch(void* const* d_in, const int* in_sizes, int n_in,
                              void* d_out, int out_size, void* d_ws, size_t ws_size,
                              hipStream_t stream)
{
  const float* x_user  = (const float*)d_in[0];
  const float* x_item  = (const float*)d_in[1];
  const int*   esrc    = (const int*)d_in[2];
  const int*   edst    = (const int*)d_in[3];
  const float* W_l1_ui = (const float*)d_in[4];
  const float* W_r1_ui = (const float*)d_in[5];
  const float* b_l1_ui = (const float*)d_in[6];
  const float* W_l1_iu = (const float*)d_in[7];
  const float* W_r1_iu = (const float*)d_in[8];
  const float* b_l1_iu = (const float*)d_in[9];
  const float* W_l2_ui = (const float*)d_in[10];
  const float* W_r2_ui = (const float*)d_in[11];
  const float* b_l2_ui = (const float*)d_in[12];
  const float* W_l2_iu = (const float*)d_in[13];
  const float* W_r2_iu = (const float*)d_in[14];
  const float* b_l2_iu = (const float*)d_in[15];

  const int NU = in_sizes[0] / 128;   // 200000
  const int NI = in_sizes[1] / 128;   // 100000
  const int E  = in_sizes[2];         // 500000
  const int NA = NI + NU;
  const int MI = ((NI + 127) / 128) * 128;   // padded row counts
  const int MU = ((NU + 127) / 128) * 128;

  char* ws = (char*)d_ws;
  size_t off = 0;
  auto alloc = [&](size_t bytes) -> void* {
    void* p = ws + off;
    off += (bytes + 255) & ~(size_t)255;
    return p;
  };

  // --- zeroed-every-launch region ---
  int* cntAll = (int*)alloc((size_t)NA * 4);
  int* curAll = (int*)alloc((size_t)NA * 4);
  size_t zeroBytes = off;
  // --- CSR ---
  int* offAll   = (int*)alloc((size_t)(NA + 1) * 4);
  int* tileSums = (int*)alloc(256 * 4);
  int* idxAll   = (int*)alloc((size_t)2 * E * 4);
  // --- weights (bf16, frag128 split) ---
  unsigned short* T1ui_l  = (unsigned short*)alloc(256 * 128 * 2);
  unsigned short* T1ui_h  = (unsigned short*)alloc(256 * 128 * 2);
  unsigned short* T1iu_l  = (unsigned short*)alloc(256 * 128 * 2);
  unsigned short* T1iu_h  = (unsigned short*)alloc(256 * 128 * 2);
  unsigned short* T2lui_l = (unsigned short*)alloc(128 * 128 * 2);
  unsigned short* T2lui_h = (unsigned short*)alloc(128 * 128 * 2);
  unsigned short* T2rui_l = (unsigned short*)alloc(128 * 128 * 2);
  unsigned short* T2rui_h = (unsigned short*)alloc(128 * 128 * 2);
  unsigned short* T2liu_l = (unsigned short*)alloc(128 * 128 * 2);
  unsigned short* T2liu_h = (unsigned short*)alloc(128 * 128 * 2);
  unsigned short* T2riu_l = (unsigned short*)alloc(128 * 128 * 2);
  unsigned short* T2riu_h = (unsigned short*)alloc(128 * 128 * 2);
  // --- hidden states (frag128 split lo|hi, padded rows) ---
  unsigned short* h_item = (unsigned short*)alloc((size_t)MI * 256 * 2);
  unsigned short* h_item_hi = h_item + (size_t)MI * 128;
  unsigned short* h_user = (unsigned short*)alloc((size_t)MU * 256 * 2);
  unsigned short* h_user_hi = h_user + (size_t)MU * 128;
  // --- time-shared region R ---
  char* R = (char*)alloc((size_t)(MI + MU) * 256 * 2);
  // layer-1 phase: [Mf_item | Mf_user | Xf_item | Xf_user], each M*128 bf16
  unsigned short* Mf_item = (unsigned short*)R;
  unsigned short* Mf_user = (unsigned short*)(R + (size_t)MI * 128 * 2);
  unsigned short* Xf_item = (unsigned short*)(R + (size_t)(MI + MU) * 128 * 2);
  unsigned short* Xf_user = (unsigned short*)(R + (size_t)(2 * MI + MU) * 128 * 2);
  // layer-2 phase (layer-1 temporaries dead after L1 GEMMs); row-major:
  unsigned short* p_user = (unsigned short*)R;                                    // NU*128 bf16
  unsigned short* p_item = (unsigned short*)(R + (size_t)NU * 128 * 2);           // NI*128 bf16
  unsigned short* m2I    = (unsigned short*)(R + (size_t)(NU + NI) * 128 * 2);    // NI*128 bf16
  unsigned short* m2U    = (unsigned short*)(R + (size_t)(NU + 2 * NI) * 128 * 2);// NU*128 bf16

  float* out = (float*)d_out;   // [o_user (NU*128) | o_item (NI*128)] fp32

  // 1) zero counts/cursors
  hipMemsetAsync(ws, 0, zeroBytes, stream);

  // 2) weight transposes -> frag128 split (single launch)
  build_wt_all<<<1024, 256, 0, stream>>>(
      W_l1_ui, W_r1_ui, W_l1_iu, W_r1_iu, W_l2_ui, W_r2_ui, W_l2_iu, W_r2_iu,
      T1ui_l, T1ui_h, T1iu_l, T1iu_h,
      T2lui_l, T2lui_h, T2rui_l, T2rui_h, T2liu_l, T2liu_h, T2riu_l, T2riu_h);

  // 3) streaming self-feature conversion -> Xfrag (independent of CSR)
  int units = (MI + MU) * 16;
  conv_x<<<(units + 255) / 256, 256, 0, stream>>>(
      x_user, x_item, (uint4*)Xf_item, (uint4*)Xf_user, NI, NU, MI, MU);

  // 4) CSR build: hist -> 3-pass scan -> fill
  int egrid = (E + 255) / 256;
  int nTiles = (NA + SCAN_TILE - 1) / SCAN_TILE;
  hist<<<egrid, 256, 0, stream>>>(esrc, edst, cntAll, NI, E);
  scan_p1<<<nTiles, 256, 0, stream>>>(cntAll, tileSums, NA);
  scan_p2<<<1, 256, 0, stream>>>(tileSums, nTiles, offAll + NA);
  scan_p3<<<nTiles, 256, 0, stream>>>(cntAll, tileSums, offAll, NA);
  fill_idx<<<egrid, 256, 0, stream>>>(esrc, edst, offAll, curAll, idxAll, NI, E);

  // 5) layer-1 neighbor means -> Mfrag (gather-only, 2 nodes/wave)
  int waves1 = (NA + 1) / 2;
  build_mean<<<(waves1 * 64 + 255) / 256, 256, 0, stream>>>(
      x_user, x_item, idxAll, offAll, Mf_item, Mf_user, NI, NA);

  // 6) layer-1 GEMMs: h = relu([mean @ Wl] + [x @ Wr] + b), frag128 out
  dim3 gI(MI / 128, 2), gU(MU / 128, 2);
  gemm_flat<<<gI, 256, 0, stream>>>(Mf_item, Xf_item, T1ui_l, T1ui_h, b_l1_ui,
                                    nullptr, h_item, h_item_hi, 0, 1, NI, 256, 1);
  gemm_flat<<<gU, 256, 0, stream>>>(Mf_user, Xf_user, T1iu_l, T1iu_h, b_l1_iu,
                                    nullptr, h_user, h_user_hi, 0, 1, NU, 256, 1);

  // 7) layer-2 left-projections: p = h @ W_l2, row-major bf16
  dim3 pGu(MU / 128, 1), pGi(MI / 128, 1);
  gemm_flat<<<pGu, 256, 0, stream>>>(h_user, h_user_hi, T2lui_l, T2lui_h, nullptr,
                                     nullptr, p_user, nullptr, 0, 0, NU, 128, 0);
  gemm_flat<<<pGi, 256, 0, stream>>>(h_item, h_item_hi, T2liu_l, T2liu_h, nullptr,
                                     nullptr, p_item, nullptr, 0, 0, NI, 128, 0);

  // 8) layer-2 aggregation (4 nodes/wave)
  int waves2 = (NA + 3) / 4;
  seg_mean<<<(waves2 * 64 + 255) / 256, 256, 0, stream>>>(
      (const unsigned int*)p_user, (const unsigned int*)p_item,
      idxAll, offAll, (unsigned int*)m2I, (unsigned int*)m2U, NI, NA);

  // 9) output GEMMs: o = relu(h @ W_r2 + m2 + b), fp32 row-major out
  gemm_flat<<<pGi, 256, 0, stream>>>(h_item, h_item_hi, T2rui_l, T2rui_h, b_l2_ui,
                                     m2I, out + (size_t)NU * 128, nullptr, 1, 0, NI, 128, 1);
  gemm_flat<<<pGu, 256, 0, stream>>>(h_user, h_user_hi, T2riu_l, T2riu_h, b_l2_iu,
                                     m2U, out, nullptr, 1, 0, NU, 128, 1);
}